// Round 3
// baseline (559.808 us; speedup 1.0000x reference)
//
#include <hip/hip_runtime.h>
#include <stdint.h>

// ---------------------------------------------------------------------------
// scores[b,s] = v . tanh( hidden[b] @ Wh + bias + enc[s,b] @ We )
// out[b,s]   = softmax_s(scores)
// Big GEMM: enc_flat[M=65536,K=1024] @ We[K=1024,N=512], bf16 MFMA.
// R3: BARRIERLESS K-loop. A-fragments are 32 contiguous bytes/lane of an enc
//     row -> load global->VGPR directly (no LDS, no __syncthreads in loop).
//     4x wave redundancy on A is absorbed by L2. Plain register deps let the
//     compiler emit fine-grained vmcnt(N); each wave keeps 8KB A in flight.
// ---------------------------------------------------------------------------

typedef float  floatx4 __attribute__((ext_vector_type(4)));
typedef float  floatx8 __attribute__((ext_vector_type(8)));
typedef __bf16 bf16x8  __attribute__((ext_vector_type(8)));
typedef short  short8  __attribute__((ext_vector_type(8)));

union bfu { bf16x8 v; short8 s; };

#define LOG2E_X2 2.8853900817779268f

// ---- kernel 0: W[512:1536,:] -> bf16 transposed Wt[n][k], LDS-tiled 64x64.
__global__ void wt_convert(const float* __restrict__ W, __bf16* __restrict__ Wt) {
  __shared__ float tile[64][65];
  const int kt = blockIdx.x >> 3;                // 16 k-tiles
  const int nt = blockIdx.x & 7;                 // 8 n-tiles
  const int c  = threadIdx.x & 63;
  const int r4 = threadIdx.x >> 6;
  #pragma unroll 4
  for (int i = 0; i < 16; i++) {
    int r = i * 4 + r4;
    tile[r][c] = W[(long)(512 + kt * 64 + r) * 512 + nt * 64 + c];
  }
  __syncthreads();
  #pragma unroll 4
  for (int i = 0; i < 16; i++) {
    int n = i * 4 + r4;
    Wt[(long)(nt * 64 + n) * 1024 + kt * 64 + c] = (__bf16)tile[c][n];
  }
}

// ---- kernel 1: hproj[b][n] = bias[n] + sum_k hidden[b,k] * W[k,n]  (k<512)
__global__ void hproj_kernel(const float* __restrict__ hidden,
                             const float* __restrict__ W,
                             const float* __restrict__ bias,
                             float* __restrict__ hproj) {
  const int tid = threadIdx.x;            // n
  const int b_  = blockIdx.x >> 2;
  const int kc  = blockIdx.x & 3;
  __shared__ float hid[128];
  if (tid < 128) hid[tid] = hidden[b_ * 512 + kc * 128 + tid];
  __syncthreads();
  float acc = (kc == 0) ? bias[tid] : 0.f;
  const float* Wp = W + (long)(kc * 128) * 512 + tid;
  #pragma unroll 8
  for (int k = 0; k < 128; k++) acc = fmaf(hid[k], Wp[(long)k * 512], acc);
  atomicAdd(&hproj[b_ * 512 + tid], acc);
}

// ---- kernel 2: big GEMM + tanh/v-dot epilogue, barrierless K-loop
__global__ __launch_bounds__(256, 2) void gemm_score(
    const float* __restrict__ enc,    // [65536][1024] fp32
    const __bf16* __restrict__ Wt,    // [512][1024] bf16 (n-major)
    const float* __restrict__ hproj,  // [64][512]
    const float* __restrict__ v,      // [512]
    float* __restrict__ scores)       // [64][1024]  ([b][s])
{
  __shared__ float bscore[64];

  const int tid  = threadIdx.x;
  const int lane = tid & 63;
  const int wv   = tid >> 6;      // wave -> n-range [wv*128, wv*128+128)
  const int q    = lane >> 4;
  const int t    = lane & 15;
  const long m0  = (long)blockIdx.x * 64;

  if (tid < 64) bscore[tid] = 0.f;

  // A row base for rt: enc[(m0 + rt*16 + t)*1024 + q*8 + kk]  (32B/lane)
  const float* aptr[4];
  #pragma unroll
  for (int rt = 0; rt < 4; rt++)
    aptr[rt] = enc + (m0 + rt * 16 + t) * 1024 + q * 8;
  // B base for ct: Wt[(wv*128 + ct*16 + t)*1024 + q*8 + kk]  (16B/lane)
  const __bf16* bptr[8];
  #pragma unroll
  for (int ct = 0; ct < 8; ct++)
    bptr[ct] = Wt + (long)(wv * 128 + ct * 16 + t) * 1024 + q * 8;

  floatx4 acc[4][8];
  #pragma unroll
  for (int i = 0; i < 4; i++)
    #pragma unroll
    for (int j = 0; j < 8; j++)
      acc[i][j] = (floatx4){0.f, 0.f, 0.f, 0.f};

  auto loadA = [&](int kk, floatx8* ar) {
    #pragma unroll
    for (int rt = 0; rt < 4; rt++) ar[rt] = *(const floatx8*)(aptr[rt] + kk);
  };
  auto cvtA = [&](const floatx8* ar, short8* af) {
    #pragma unroll
    for (int rt = 0; rt < 4; rt++) {
      union bfu u;
      #pragma unroll
      for (int j = 0; j < 8; j++) u.v[j] = (__bf16)ar[rt][j];
      af[rt] = u.s;
    }
  };

  floatx8 ar[4];
  short8  b0[8], b1[8], af[4];

  loadA(0, ar);
  #pragma unroll
  for (int ct = 0; ct < 8; ct++) {
    union bfu u; u.v = *(const bf16x8*)(bptr[ct]); b0[ct] = u.s;
  }

  // 32 K-steps of 32, 2x unrolled ping-pong, NO barriers.
  // Per phase: convert current A (frees ar), prefetch next A into ar,
  // MFMA over ct with rolling B prefetch (b_next[ct] issued as b_cur[ct] dies).
  for (int T = 0; T < 16; T++) {
    const int kk = T * 64;

    cvtA(ar, af);
    loadA(kk + 32, ar);
    #pragma unroll
    for (int ct = 0; ct < 8; ct++) {
      #pragma unroll
      for (int rt = 0; rt < 4; rt++)
        acc[rt][ct] = __builtin_amdgcn_mfma_f32_16x16x32_bf16(
            af[rt], b0[ct], acc[rt][ct], 0, 0, 0);
      union bfu u; u.v = *(const bf16x8*)(bptr[ct] + kk + 32); b1[ct] = u.s;
    }

    cvtA(ar, af);
    if (T < 15) loadA(kk + 64, ar);
    #pragma unroll
    for (int ct = 0; ct < 8; ct++) {
      #pragma unroll
      for (int rt = 0; rt < 4; rt++)
        acc[rt][ct] = __builtin_amdgcn_mfma_f32_16x16x32_bf16(
            af[rt], b1[ct], acc[rt][ct], 0, 0, 0);
      if (T < 15) {
        union bfu u; u.v = *(const bf16x8*)(bptr[ct] + kk + 64); b0[ct] = u.s;
      }
    }
  }

  __syncthreads();   // bscore init visible before epilogue atomics

  // ---- epilogue: score[row] = sum_n v[n] * tanh(acc + hproj[row][n])
  float vv[8];
  #pragma unroll
  for (int ct = 0; ct < 8; ct++) vv[ct] = v[wv * 128 + ct * 16 + t];

  #pragma unroll
  for (int rt = 0; rt < 4; rt++) {
    #pragma unroll
    for (int r = 0; r < 4; r++) {
      int row = rt * 16 + q * 4 + r;              // C/D: row=(lane>>4)*4+reg
      const float* hrow = hproj + row * 512 + wv * 128 + t;
      float s = 0.f;
      #pragma unroll
      for (int ct = 0; ct < 8; ct++) {
        float e  = acc[rt][ct][r] + hrow[ct * 16];
        float ex = __builtin_amdgcn_exp2f(e * LOG2E_X2);        // e^(2x)
        float th = 1.f - 2.f * __builtin_amdgcn_rcpf(ex + 1.f); // tanh(x)
        s = fmaf(vv[ct], th, s);
      }
      s += __shfl_xor(s, 1);
      s += __shfl_xor(s, 2);
      s += __shfl_xor(s, 4);
      s += __shfl_xor(s, 8);
      if (t == 0) atomicAdd(&bscore[row], s);
    }
  }
  __syncthreads();
  if (tid < 64) scores[(long)tid * 1024 + blockIdx.x] = bscore[tid];
}

// ---- kernel 3: softmax over s for each b
__global__ void softmax_kernel(const float* __restrict__ scores,
                               float* __restrict__ out) {
  const int b_   = blockIdx.x;
  const int tid  = threadIdx.x;
  const int lane = tid & 63;
  const int wv   = tid >> 6;
  __shared__ float redmax[4], redsum[4];

  float x[4];
  #pragma unroll
  for (int i = 0; i < 4; i++) x[i] = scores[b_ * 1024 + i * 256 + tid];
  float mx = fmaxf(fmaxf(x[0], x[1]), fmaxf(x[2], x[3]));
  #pragma unroll
  for (int off = 1; off < 64; off <<= 1) mx = fmaxf(mx, __shfl_xor(mx, off));
  if (lane == 0) redmax[wv] = mx;
  __syncthreads();
  mx = fmaxf(fmaxf(redmax[0], redmax[1]), fmaxf(redmax[2], redmax[3]));

  float e[4], s = 0.f;
  #pragma unroll
  for (int i = 0; i < 4; i++) { e[i] = __expf(x[i] - mx); s += e[i]; }
  #pragma unroll
  for (int off = 1; off < 64; off <<= 1) s += __shfl_xor(s, off);
  if (lane == 0) redsum[wv] = s;
  __syncthreads();
  s = redsum[0] + redsum[1] + redsum[2] + redsum[3];
  float inv = 1.f / s;
  #pragma unroll
  for (int i = 0; i < 4; i++) out[b_ * 1024 + i * 256 + tid] = e[i] * inv;
}

extern "C" void kernel_launch(void* const* d_in, const int* in_sizes, int n_in,
                              void* d_out, int out_size, void* d_ws, size_t ws_size,
                              hipStream_t stream) {
  (void)in_sizes; (void)n_in; (void)out_size; (void)ws_size;
  const float* hidden = (const float*)d_in[0];   // [64,512]
  const float* enc    = (const float*)d_in[1];   // [1024,64,1024]
  const float* W      = (const float*)d_in[2];   // [1536,512]
  const float* bias   = (const float*)d_in[3];   // [512]
  const float* v      = (const float*)d_in[4];   // [512]
  float* out = (float*)d_out;                    // [64,1024]

  char* ws = (char*)d_ws;
  __bf16* Wt    = (__bf16*)ws;                            // 1 MB
  float*  hproj = (float*)(ws + (1 << 20));               // 128 KB
  float*  scores= (float*)(ws + (1 << 20) + (128 << 10)); // 256 KB

  hipMemsetAsync(hproj, 0, 64 * 512 * sizeof(float), stream);
  wt_convert<<<128, 256, 0, stream>>>(W, Wt);
  hproj_kernel<<<256, 512, 0, stream>>>(hidden, W, bias, hproj);
  gemm_score<<<1024, 256, 0, stream>>>(enc, Wt, hproj, v, scores);
  softmax_kernel<<<64, 256, 0, stream>>>(scores, out);
}